// Round 3
// baseline (3765.326 us; speedup 1.0000x reference)
//
#include <hip/hip_runtime.h>
#include <math.h>

#define LN   720
#define NBIN 361
#define CCH  128
#define NPAIRS 8128   // 128*127/2
#define NP     12     // pairs per k_pc block
#define NPG    678    // ceil(8128/12)
#define KCH    128    // k-chunk size for staged cross (3 chunks cover 361 bins)

// ---------------------------------------------------------------- tables
__global__ void k_twiddle(double* __restrict__ ct, double* __restrict__ st) {
  int m = blockIdx.x * 256 + threadIdx.x;
  if (m < LN) {
    double a = 6.2831853071795864769252867665590057684 * (double)m / 720.0;
    ct[m] = cos(a);
    st[m] = sin(a);
  }
}

// Cm[k*720+n] = ct[(k*n)%720], Sm likewise — bit-identical to the LDS gather values.
__global__ void k_wmat(const double* __restrict__ ct, const double* __restrict__ st,
                       double* __restrict__ Cm, double* __restrict__ Sm) {
  int idx = blockIdx.x * 256 + threadIdx.x;
  if (idx < NBIN * LN) {
    int k = idx / LN, n = idx - k * LN;
    int r = (int)(((long long)k * n) % LN);
    Cm[idx] = ct[r];
    Sm[idx] = st[r];
  }
}

__global__ void k_ptab(int2* __restrict__ ptab) {
  int p = blockIdx.x * 256 + threadIdx.x;
  if (p < NPAIRS) {
    int i = 0, rem = p;
    while (rem >= 127 - i) { rem -= 127 - i; i++; }
    ptab[p] = make_int2(i, i + 1 + rem);
  }
}

__global__ void k_dctmat(float* __restrict__ D) {
  int idx = blockIdx.x * 256 + threadIdx.x;
  if (idx < LN * LN) {
    int k = idx / LN, l = idx - k * LN;
    double ang = 3.1415926535897932384626433832795028842 * (double)((2 * l + 1) * k) / 1440.0;
    double v = cos(ang) * sqrt(2.0 / 720.0);
    if (k == 0) v *= 0.70710678118654752440084436210485;
    D[idx] = (float)v;
  }
}

// ---------------------------------------------------------------- rfft (fp64 backbone) -> fp32-quantized nrf
__global__ __launch_bounds__(256) void k_rfft(const float* __restrict__ x,
                                              const double* __restrict__ ctg,
                                              const double* __restrict__ stg,
                                              float* __restrict__ nR,
                                              float* __restrict__ nI) {
  __shared__ double sd[LN];
  __shared__ double ctsP[768], stsP[768];
  int b = blockIdx.x >> 7, c = blockIdx.x & 127;
  int t = threadIdx.x;
  for (int m = t; m < LN; m += 256) {
    int a = m + (m >> 4);
    ctsP[a] = ctg[m]; stsP[a] = stg[m];
  }
  for (int l = t; l < LN; l += 256) sd[l] = (double)x[(b * LN + l) * CCH + c];
  __syncthreads();
  size_t gbase = (size_t)blockIdx.x * NBIN;
  for (int k = t; k < NBIN; k += 256) {
    double re = 0.0, im = 0.0;
    int idx = 0;
    for (int l = 0; l < LN; l++) {
      double s = sd[l];
      int a = idx + (idx >> 4);
      re += s * ctsP[a];
      im -= s * stsP[a];
      idx += k; if (idx >= LN) idx -= LN;
    }
    float reF = (float)re, imF = (float)im;        // complex64 quantization of rf
    float mag = hypotf(reF, imF);
    float d = fmaxf(mag, 1e-8f);
    nR[gbase + k] = __fdiv_rn(reF, d);
    nI[gbase + k] = __fdiv_rn(imF, d);
  }
}

// ---------------------------------------------------------------- phase correlation (GEMM-style)
// cross in strict fp32 (frozen invariant), irfft backbone fp64, k-ascending per
// accumulator. pc fp32-quantized before max/argmax; ties -> lowest index.
//
// Round 8: exploit C(k,720-n)=C(k,n), S(k,720-n)=-S(k,n). Accumulate
// cosA = sum cr*C and sinA = sum ci*S for n=0..360 only; then
//   pc[n]     = (dc + sgn*ny + 2*(cosA - sinA))/720
//   pc[720-n] = (dc + sgn*ny + 2*(cosA + sinA))/720
// Halves the fp64 FMA work and cuts table loads 6->2 per k-iter (table
// footprint ~2.2MB -> XCD-L2-resident). 384 threads/block, thread t owns
// bin n=t (t<361; spare lanes compute discarded garbage from in-bounds cols).
// Rounding differs ~1e-15 rel from the interleaved chain; survives the fp32
// quantization unchanged.
__global__ __launch_bounds__(384, 4) void k_pc(const float* __restrict__ nR,
                                               const float* __restrict__ nI,
                                               const double* __restrict__ Cm,
                                               const double* __restrict__ Sm,
                                               const int2* __restrict__ ptab,
                                               float* __restrict__ Mv, int* __restrict__ Mi) {
  __shared__ double2 cC[NP][KCH];        // .x = Re, .y = Im (one k-chunk at a time)
  __shared__ int2 spair[NP];
  __shared__ float wv[6][NP][2];
  __shared__ int   wi[6][NP][2];
  __shared__ double sdc[NP], sny[NP];    // k=0 (dc) and k=360 (nyquist) Re terms
  int b = blockIdx.x / NPG;
  int pg = blockIdx.x - b * NPG;
  int pbase = pg * NP;
  int np = NPAIRS - pbase; if (np > NP) np = NP;
  int t = threadIdx.x;
  if (t < np) spair[t] = ptab[pbase + t];
  __syncthreads();

  // thread t owns bin n = t (valid for t < 361; t in 361..383 is in-bounds garbage)
  int n0 = t;
  double cosA[NP], sinA[NP];
#pragma unroll
  for (int p = 0; p < NP; p++) { cosA[p] = 0.0; sinA[p] = 0.0; }

  for (int ch = 0; ch < 3; ch++) {
    int klo = ch * KCH;
    // stage this k-chunk of cross (strict fp32, upcast to fp64)
    for (int v = t; v < np * KCH; v += 384) {
      int p = v >> 7, kk = v & (KCH - 1);
      int k = klo + kk;
      if (k < NBIN) {
        int i = spair[p].x, j = spair[p].y;
        size_t ib = ((size_t)(b << 7) + i) * NBIN + k;
        size_t jb = ((size_t)(b << 7) + j) * NBIN + k;
        float aR = nR[ib], aI = nI[ib];
        float bR = nR[jb], bI = nI[jb];
        float xr = __fadd_rn(__fmul_rn(aR, bR), __fmul_rn(aI, bI));
        float xi = __fsub_rn(__fmul_rn(aI, bR), __fmul_rn(aR, bI));
        cC[p][kk] = make_double2((double)xr, (double)xi);
        if (k == 0)   sdc[p] = (double)xr;
        if (k == 360) sny[p] = (double)xr;
      }
    }
    __syncthreads();

    int kstart = (klo < 1) ? 1 : klo;
    int kend = klo + KCH; if (kend > 360) kend = 360;
#pragma unroll 2
    for (int k = kstart; k < kend; k++) {
      const double* Cr = Cm + (size_t)k * LN;
      const double* Sr = Sm + (size_t)k * LN;
      double C0 = Cr[n0];
      double S0 = Sr[n0];
      int kk = k - klo;
#pragma unroll
      for (int p = 0; p < NP; p++) {
        double2 cx = cC[p][kk];
        cosA[p] = fma(cx.x, C0, cosA[p]);
        sinA[p] = fma(cx.y, S0, sinA[p]);
      }
    }
    __syncthreads();
  }

  // epilogue: fp32 quantize + argmax (both directions)
  float b1v[NP], b2v[NP]; int b1i[NP], b2i[NP];
#pragma unroll
  for (int p = 0; p < NP; p++) { b1v[p] = -3.0e38f; b2v[p] = -3.0e38f; b1i[p] = 0x7fffffff; b2i[p] = 0x7fffffff; }
  if (t < NBIN) {
    int n = t;
    bool hasRev = (n >= 1) && (n <= 359);  // n=0 invalid; n=360 duplicate of fwd
    int idxF1 = n;                          // d0 index of pf_f
    int idxR1 = LN - n;                     // d0 index of pf_r
    int idxF2 = (n == 0) ? 0 : (LN - n);    // d1 index of pf_f
    int idxR2 = n;                          // d1 index of pf_r
#pragma unroll
    for (int p = 0; p < NP; p++) {
      double dc = sdc[p], ny = sny[p];
      double sg = (n & 1) ? -ny : ny;
      double ca = cosA[p], sa = sinA[p];
      float pf_f = (float)((dc + sg + 2.0 * (ca - sa)) * (1.0 / 720.0));
      float pf_r = (float)((dc + sg + 2.0 * (ca + sa)) * (1.0 / 720.0));
      b1v[p] = pf_f; b1i[p] = idxF1;
      if (hasRev && (pf_r > b1v[p] || (pf_r == b1v[p] && idxR1 < b1i[p]))) { b1v[p] = pf_r; b1i[p] = idxR1; }
      b2v[p] = pf_f; b2i[p] = idxF2;
      if (hasRev && (pf_r > b2v[p] || (pf_r == b2v[p] && idxR2 < b2i[p]))) { b2v[p] = pf_r; b2i[p] = idxR2; }
    }
  }
  int lane = t & 63, w = t >> 6;
#pragma unroll
  for (int p = 0; p < NP; p++) {
    for (int off = 32; off >= 1; off >>= 1) {
      float ov = __shfl_down(b1v[p], off); int oi = __shfl_down(b1i[p], off);
      if (ov > b1v[p] || (ov == b1v[p] && oi < b1i[p])) { b1v[p] = ov; b1i[p] = oi; }
      float ov2 = __shfl_down(b2v[p], off); int oi2 = __shfl_down(b2i[p], off);
      if (ov2 > b2v[p] || (ov2 == b2v[p] && oi2 < b2i[p])) { b2v[p] = ov2; b2i[p] = oi2; }
    }
    if (lane == 0) {
      wv[w][p][0] = b1v[p]; wi[w][p][0] = b1i[p];
      wv[w][p][1] = b2v[p]; wi[w][p][1] = b2i[p];
    }
  }
  __syncthreads();
  if (t < NP * 2) {
    int p = t >> 1, d = t & 1;
    if (p < np) {
      float bv = wv[0][p][d]; int bi = wi[0][p][d];
      for (int ww = 1; ww < 6; ww++) {
        float ov = wv[ww][p][d]; int oi = wi[ww][p][d];
        if (ov > bv || (ov == bv && oi < bi)) { bv = ov; bi = oi; }
      }
      int i = spair[p].x, j = spair[p].y;
      int o = d ? ((((b << 7) + j) << 7) + i) : ((((b << 7) + i) << 7) + j);
      Mv[o] = bv; Mi[o] = bi;
    }
  }
}

// ---------------------------------------------------------------- top-8 (fp32, literal selection)
__global__ __launch_bounds__(64) void k_topk(const float* __restrict__ Mv, const int* __restrict__ Mi,
                                             int* __restrict__ lid, int* __restrict__ shf,
                                             float* __restrict__ rv) {
  int b = blockIdx.x >> 7, r = blockIdx.x & 127;
  if (threadIdx.x != 0) return;
  float sval[128]; int ssh[128];
  int base = (((b << 7) + r) << 7);
  for (int j = 0; j < 128; j++) {
    if (j == r) { sval[j] = -3.0e38f; ssh[j] = 0; continue; }
    float mvv = Mv[base + j]; int mii = Mi[base + j];
    sval[j] = mvv;
    ssh[j] = (mii > 360) ? (mii - 720) : mii;
  }
  for (int k = 0; k < 8; k++) {
    float best = -3.0e38f; int bj = 0;
    for (int j = 0; j < 128; j++)
      if (sval[j] > best) { best = sval[j]; bj = j; }
    int o = (((b << 7) + r) << 3) + k;
    lid[o] = bj; rv[o] = best; shf[o] = ssh[bj];
    sval[bj] = -3.0e38f;
  }
}

// ---------------------------------------------------------------- gather + DCT + bands (fp32, staged)
__global__ __launch_bounds__(256) void k_out(const float* __restrict__ x,
                                             const float* __restrict__ D,
                                             const int* __restrict__ lid,
                                             const int* __restrict__ shf,
                                             const float* __restrict__ rv,
                                             float* __restrict__ out) {
  __shared__ float Xs[9][LN];
  __shared__ float pool[9216];   // phase1/2: xe[9*720]; phase3: obuf[256*36]
  __shared__ int s_lid[8], s_shf[8];
  __shared__ float s_r[8];
  int b = blockIdx.x >> 7, c = blockIdx.x & 127;
  int t = threadIdx.x;
  if (t < 8) {
    int q = (((b << 7) + c) << 3) + t;
    s_lid[t] = lid[q]; s_shf[t] = shf[q]; s_r[t] = rv[q];
  }
  float* xe = pool;
  for (int l = t; l < LN; l += 256) xe[l] = x[(b * LN + l) * CCH + c];
  __syncthreads();
  for (int p = 1; p <= 8; p++) {
    float r = s_r[p - 1];
    if (fabsf(r) < 0.1f) {
      for (int l = t; l < LN; l += 256) xe[p * LN + l] = xe[l];
    } else {
      float sg = (r < 0.f) ? -1.f : 1.f;
      int ld = s_lid[p - 1], sh = s_shf[p - 1];
      for (int l = t; l < LN; l += 256) {
        int tt = l - sh; tt = tt < 0 ? 0 : (tt > 719 ? 719 : tt);
        xe[p * LN + l] = sg * x[(b * LN + tt) * CCH + ld];
      }
    }
  }
  __syncthreads();

  // Phase 2: X[p,k] = sum_l D[k,l]*xe[p,l]
  {
    int k0 = t, k1 = t + 256, k2 = t + 512;
    float a0[9], a1[9], a2[9];
#pragma unroll
    for (int p = 0; p < 9; p++) { a0[p] = 0.f; a1[p] = 0.f; a2[p] = 0.f; }
    const float* D0 = D + (size_t)k0 * LN;
    const float* D1 = D + (size_t)k1 * LN;
    const float* D2 = D + (size_t)(k2 < LN ? k2 : k0) * LN;
    for (int l = 0; l < LN; l++) {
      float xl[9];
#pragma unroll
      for (int p = 0; p < 9; p++) xl[p] = xe[p * LN + l];
      float d0 = D0[l], d1 = D1[l], d2 = D2[l];
#pragma unroll
      for (int p = 0; p < 9; p++) {
        a0[p] += d0 * xl[p];
        a1[p] += d1 * xl[p];
        a2[p] += d2 * xl[p];
      }
    }
#pragma unroll
    for (int p = 0; p < 9; p++) {
      Xs[p][k0] = a0[p];
      Xs[p][k1] = a1[p];
      if (k2 < LN) Xs[p][k2] = a2[p];
    }
  }
  __syncthreads();

  // Phase 3: bands, chunked over n for coalesced output
  float* obuf = pool;
  size_t outbase = (size_t)((b << 7) + c) * (LN * 36);
  for (int n0 = 0; n0 < LN; n0 += 256) {
    int nt = t & 63;
    int f = t >> 6;
    int nloc = nt * 4;
    int nchunk = (LN - n0 < 256) ? (LN - n0) : 256;
    bool act = (nloc < nchunk);
    float a[36];
#pragma unroll
    for (int q = 0; q < 36; q++) a[q] = 0.f;
    if (act) {
      const float* Dp = D + (size_t)(f * 180) * LN + (n0 + nloc);
      for (int k = 0; k < 180; k++) {
        float4 d = *(const float4*)Dp;
        Dp += LN;
        int kk = f * 180 + k;
#pragma unroll
        for (int p = 0; p < 9; p++) {
          float xv = Xs[p][kk];
          a[p * 4 + 0] += d.x * xv;
          a[p * 4 + 1] += d.y * xv;
          a[p * 4 + 2] += d.z * xv;
          a[p * 4 + 3] += d.w * xv;
        }
      }
#pragma unroll
      for (int p = 0; p < 9; p++)
#pragma unroll
        for (int nn = 0; nn < 4; nn++)
          obuf[(nloc + nn) * 36 + p * 4 + f] = a[p * 4 + nn];
    }
    __syncthreads();
    int tot = nchunk * 36;
    for (int idx = t; idx < tot; idx += 256)
      out[outbase + (size_t)n0 * 36 + idx] = obuf[idx];
    __syncthreads();
  }
}

// ---------------------------------------------------------------- launch
extern "C" void kernel_launch(void* const* d_in, const int* in_sizes, int n_in,
                              void* d_out, int out_size, void* d_ws, size_t ws_size,
                              hipStream_t stream) {
  const float* x = (const float*)d_in[0];
  float* out = (float*)d_out;

  char* ws = (char*)d_ws;
  double* ct  = (double*)ws;                      // 720
  double* st  = ct + 720;                         // 720
  double* Cm  = st + 720;                         // 361*720
  double* Sm  = Cm + NBIN * LN;                   // 361*720
  float*  nRr = (float*)(Sm + NBIN * LN);         // 1024*361
  float*  nIr = nRr + 1024 * NBIN;                // 1024*361
  float*  Mv  = nIr + 1024 * NBIN;                // 8*128*128
  float*  rv  = Mv + 8 * 128 * 128;               // 8*128*8
  float*  D   = rv + 8 * 128 * 8;                 // 720*720 (16B-aligned)
  int*    Mi  = (int*)(D + 720 * 720);            // 8*128*128
  int*    lid = Mi + 8 * 128 * 128;               // 8*128*8
  int*    shf = lid + 8 * 128 * 8;                // 8*128*8
  int2*   ptab = (int2*)(shf + 8 * 128 * 8);      // 8128

  k_twiddle<<<3, 256, 0, stream>>>(ct, st);
  k_wmat<<<(NBIN * LN + 255) / 256, 256, 0, stream>>>(ct, st, Cm, Sm);
  k_ptab<<<(NPAIRS + 255) / 256, 256, 0, stream>>>(ptab);
  k_dctmat<<<(720 * 720 + 255) / 256, 256, 0, stream>>>(D);
  k_rfft<<<8 * 128, 256, 0, stream>>>(x, ct, st, nRr, nIr);
  k_pc<<<8 * NPG, 384, 0, stream>>>(nRr, nIr, Cm, Sm, ptab, Mv, Mi);
  k_topk<<<8 * 128, 64, 0, stream>>>(Mv, Mi, lid, shf, rv);
  k_out<<<8 * 128, 256, 0, stream>>>(x, D, lid, shf, rv, out);
}

// Round 4
// 2552.430 us; speedup vs baseline: 1.4752x; 1.4752x over previous
//
#include <hip/hip_runtime.h>
#include <math.h>

#define LN   720
#define NBIN 361
#define CCH  128
#define NPAIRS 8128   // 128*127/2
#define NP     10     // pairs per k_pc block
#define NPG    813    // ceil(8128/10)
#define KCH    128    // k-chunk size for staged cross (3 chunks cover 361 bins)

// ---------------------------------------------------------------- tables
__global__ void k_twiddle(double* __restrict__ ct, double* __restrict__ st) {
  int m = blockIdx.x * 256 + threadIdx.x;
  if (m < LN) {
    double a = 6.2831853071795864769252867665590057684 * (double)m / 720.0;
    ct[m] = cos(a);
    st[m] = sin(a);
  }
}

// Cm[k*720+n] = ct[(k*n)%720], Sm likewise — bit-identical to the LDS gather values.
__global__ void k_wmat(const double* __restrict__ ct, const double* __restrict__ st,
                       double* __restrict__ Cm, double* __restrict__ Sm) {
  int idx = blockIdx.x * 256 + threadIdx.x;
  if (idx < NBIN * LN) {
    int k = idx / LN, n = idx - k * LN;
    int r = (int)(((long long)k * n) % LN);
    Cm[idx] = ct[r];
    Sm[idx] = st[r];
  }
}

__global__ void k_ptab(int2* __restrict__ ptab) {
  int p = blockIdx.x * 256 + threadIdx.x;
  if (p < NPAIRS) {
    int i = 0, rem = p;
    while (rem >= 127 - i) { rem -= 127 - i; i++; }
    ptab[p] = make_int2(i, i + 1 + rem);
  }
}

__global__ void k_dctmat(float* __restrict__ D) {
  int idx = blockIdx.x * 256 + threadIdx.x;
  if (idx < LN * LN) {
    int k = idx / LN, l = idx - k * LN;
    double ang = 3.1415926535897932384626433832795028842 * (double)((2 * l + 1) * k) / 1440.0;
    double v = cos(ang) * sqrt(2.0 / 720.0);
    if (k == 0) v *= 0.70710678118654752440084436210485;
    D[idx] = (float)v;
  }
}

// ---------------------------------------------------------------- rfft (fp64 backbone) -> fp32-quantized nrf
__global__ __launch_bounds__(256) void k_rfft(const float* __restrict__ x,
                                              const double* __restrict__ ctg,
                                              const double* __restrict__ stg,
                                              float* __restrict__ nR,
                                              float* __restrict__ nI) {
  __shared__ double sd[LN];
  __shared__ double ctsP[768], stsP[768];
  int b = blockIdx.x >> 7, c = blockIdx.x & 127;
  int t = threadIdx.x;
  for (int m = t; m < LN; m += 256) {
    int a = m + (m >> 4);
    ctsP[a] = ctg[m]; stsP[a] = stg[m];
  }
  for (int l = t; l < LN; l += 256) sd[l] = (double)x[(b * LN + l) * CCH + c];
  __syncthreads();
  size_t gbase = (size_t)blockIdx.x * NBIN;
  for (int k = t; k < NBIN; k += 256) {
    double re = 0.0, im = 0.0;
    int idx = 0;
    for (int l = 0; l < LN; l++) {
      double s = sd[l];
      int a = idx + (idx >> 4);
      re += s * ctsP[a];
      im -= s * stsP[a];
      idx += k; if (idx >= LN) idx -= LN;
    }
    float reF = (float)re, imF = (float)im;        // complex64 quantization of rf
    float mag = hypotf(reF, imF);
    float d = fmaxf(mag, 1e-8f);
    nR[gbase + k] = __fdiv_rn(reF, d);
    nI[gbase + k] = __fdiv_rn(imF, d);
  }
}

// ---------------------------------------------------------------- phase correlation
// cross in strict fp32 (frozen invariant), irfft backbone fp64, k-ascending per
// accumulator. pc fp32-quantized before max/argmax; ties -> lowest index.
//
// Round 9: LDS-pipe wall fix. Round 8's broadcast ds_read_b128 of double2
// cross values was the per-CU bottleneck (waves x NP x 12cy per k-iter ~
// 2.3ms >> 0.43ms FMA floor). Changes:
//  - cross stored in LDS as float2 (it IS fp32 by invariant) -> ds_read_b64,
//    upcast to fp64 at the consumer (bit-identical values).
//  - 192 threads (3 waves), each thread owns 2 bins {t, t+192} of the
//    symmetric 361-bin range -> halves waves per block -> halves LDS traffic
//    per unit FMA vs round 8.
// Accumulators: cos/sin x 10 pairs x 2 bins fp64 = 80 VGPR; launch_bounds
// (192,4) caps at 128 (no spill: watch WRITE_SIZE).
__global__ __launch_bounds__(192, 4) void k_pc(const float* __restrict__ nR,
                                               const float* __restrict__ nI,
                                               const double* __restrict__ Cm,
                                               const double* __restrict__ Sm,
                                               const int2* __restrict__ ptab,
                                               float* __restrict__ Mv, int* __restrict__ Mi) {
  __shared__ float2 cC[NP][KCH];         // .x = Re, .y = Im (fp32 cross, one k-chunk)
  __shared__ int2 spair[NP];
  __shared__ float wv[3][NP][2];
  __shared__ int   wi[3][NP][2];
  __shared__ double sdc[NP], sny[NP];    // k=0 (dc) and k=360 (nyquist) Re terms
  int b = blockIdx.x / NPG;
  int pg = blockIdx.x - b * NPG;
  int pbase = pg * NP;
  int np = NPAIRS - pbase; if (np > NP) np = NP;
  int t = threadIdx.x;
  if (t < np) spair[t] = ptab[pbase + t];
  __syncthreads();

  // thread t owns bins n0 = t and n1 = t + 192 (n1 garbage when > 360; table
  // columns up to 719 exist so loads stay in-bounds, results discarded).
  int n0 = t, n1 = t + 192;
  double cosA[NP][2], sinA[NP][2];
#pragma unroll
  for (int p = 0; p < NP; p++) {
    cosA[p][0] = 0.0; cosA[p][1] = 0.0;
    sinA[p][0] = 0.0; sinA[p][1] = 0.0;
  }

  for (int ch = 0; ch < 3; ch++) {
    int klo = ch * KCH;
    // stage this k-chunk of cross (strict fp32)
    for (int v = t; v < np * KCH; v += 192) {
      int p = v >> 7, kk = v & (KCH - 1);
      int k = klo + kk;
      if (k < NBIN) {
        int i = spair[p].x, j = spair[p].y;
        size_t ib = ((size_t)(b << 7) + i) * NBIN + k;
        size_t jb = ((size_t)(b << 7) + j) * NBIN + k;
        float aR = nR[ib], aI = nI[ib];
        float bR = nR[jb], bI = nI[jb];
        float xr = __fadd_rn(__fmul_rn(aR, bR), __fmul_rn(aI, bI));
        float xi = __fsub_rn(__fmul_rn(aI, bR), __fmul_rn(aR, bI));
        cC[p][kk] = make_float2(xr, xi);
        if (k == 0)   sdc[p] = (double)xr;
        if (k == 360) sny[p] = (double)xr;
      }
    }
    __syncthreads();

    int kstart = (klo < 1) ? 1 : klo;
    int kend = klo + KCH; if (kend > 360) kend = 360;
#pragma unroll 2
    for (int k = kstart; k < kend; k++) {
      const double* Cr = Cm + (size_t)k * LN;
      const double* Sr = Sm + (size_t)k * LN;
      double C0 = Cr[n0], C1 = Cr[n1];
      double S0 = Sr[n0], S1 = Sr[n1];
      int kk = k - klo;
#pragma unroll
      for (int p = 0; p < NP; p++) {
        float2 cx = cC[p][kk];
        double cr = (double)cx.x, ci = (double)cx.y;
        cosA[p][0] = fma(cr, C0, cosA[p][0]);
        cosA[p][1] = fma(cr, C1, cosA[p][1]);
        sinA[p][0] = fma(ci, S0, sinA[p][0]);
        sinA[p][1] = fma(ci, S1, sinA[p][1]);
      }
    }
    __syncthreads();
  }

  // epilogue: fp32 quantize + argmax (both directions)
  float b1v[NP], b2v[NP]; int b1i[NP], b2i[NP];
#pragma unroll
  for (int p = 0; p < NP; p++) { b1v[p] = -3.0e38f; b2v[p] = -3.0e38f; b1i[p] = 0x7fffffff; b2i[p] = 0x7fffffff; }
#pragma unroll
  for (int q = 0; q < 2; q++) {
    int n = t + q * 192;
    if (n <= 360) {
      bool hasRev = (n >= 1) && (n <= 359);  // n=0 invalid; n=360 duplicate of fwd
      int idxF1 = n;                          // d0 index of pf_f
      int idxR1 = LN - n;                     // d0 index of pf_r
      int idxF2 = (n == 0) ? 0 : (LN - n);    // d1 index of pf_f
      int idxR2 = n;                          // d1 index of pf_r
#pragma unroll
      for (int p = 0; p < NP; p++) {
        double dc = sdc[p], ny = sny[p];
        double sg = (n & 1) ? -ny : ny;
        double ca = cosA[p][q], sa = sinA[p][q];
        float pf_f = (float)((dc + sg + 2.0 * (ca - sa)) * (1.0 / 720.0));
        float pf_r = (float)((dc + sg + 2.0 * (ca + sa)) * (1.0 / 720.0));
        if (pf_f > b1v[p] || (pf_f == b1v[p] && idxF1 < b1i[p])) { b1v[p] = pf_f; b1i[p] = idxF1; }
        if (hasRev && (pf_r > b1v[p] || (pf_r == b1v[p] && idxR1 < b1i[p]))) { b1v[p] = pf_r; b1i[p] = idxR1; }
        if (pf_f > b2v[p] || (pf_f == b2v[p] && idxF2 < b2i[p])) { b2v[p] = pf_f; b2i[p] = idxF2; }
        if (hasRev && (pf_r > b2v[p] || (pf_r == b2v[p] && idxR2 < b2i[p]))) { b2v[p] = pf_r; b2i[p] = idxR2; }
      }
    }
  }
  int lane = t & 63, w = t >> 6;
#pragma unroll
  for (int p = 0; p < NP; p++) {
    for (int off = 32; off >= 1; off >>= 1) {
      float ov = __shfl_down(b1v[p], off); int oi = __shfl_down(b1i[p], off);
      if (ov > b1v[p] || (ov == b1v[p] && oi < b1i[p])) { b1v[p] = ov; b1i[p] = oi; }
      float ov2 = __shfl_down(b2v[p], off); int oi2 = __shfl_down(b2i[p], off);
      if (ov2 > b2v[p] || (ov2 == b2v[p] && oi2 < b2i[p])) { b2v[p] = ov2; b2i[p] = oi2; }
    }
    if (lane == 0) {
      wv[w][p][0] = b1v[p]; wi[w][p][0] = b1i[p];
      wv[w][p][1] = b2v[p]; wi[w][p][1] = b2i[p];
    }
  }
  __syncthreads();
  if (t < NP * 2) {
    int p = t >> 1, d = t & 1;
    if (p < np) {
      float bv = wv[0][p][d]; int bi = wi[0][p][d];
      for (int ww = 1; ww < 3; ww++) {
        float ov = wv[ww][p][d]; int oi = wi[ww][p][d];
        if (ov > bv || (ov == bv && oi < bi)) { bv = ov; bi = oi; }
      }
      int i = spair[p].x, j = spair[p].y;
      int o = d ? ((((b << 7) + j) << 7) + i) : ((((b << 7) + i) << 7) + j);
      Mv[o] = bv; Mi[o] = bi;
    }
  }
}

// ---------------------------------------------------------------- top-8 (fp32, literal selection)
__global__ __launch_bounds__(64) void k_topk(const float* __restrict__ Mv, const int* __restrict__ Mi,
                                             int* __restrict__ lid, int* __restrict__ shf,
                                             float* __restrict__ rv) {
  int b = blockIdx.x >> 7, r = blockIdx.x & 127;
  if (threadIdx.x != 0) return;
  float sval[128]; int ssh[128];
  int base = (((b << 7) + r) << 7);
  for (int j = 0; j < 128; j++) {
    if (j == r) { sval[j] = -3.0e38f; ssh[j] = 0; continue; }
    float mvv = Mv[base + j]; int mii = Mi[base + j];
    sval[j] = mvv;
    ssh[j] = (mii > 360) ? (mii - 720) : mii;
  }
  for (int k = 0; k < 8; k++) {
    float best = -3.0e38f; int bj = 0;
    for (int j = 0; j < 128; j++)
      if (sval[j] > best) { best = sval[j]; bj = j; }
    int o = (((b << 7) + r) << 3) + k;
    lid[o] = bj; rv[o] = best; shf[o] = ssh[bj];
    sval[bj] = -3.0e38f;
  }
}

// ---------------------------------------------------------------- gather + DCT + bands (fp32, staged)
__global__ __launch_bounds__(256) void k_out(const float* __restrict__ x,
                                             const float* __restrict__ D,
                                             const int* __restrict__ lid,
                                             const int* __restrict__ shf,
                                             const float* __restrict__ rv,
                                             float* __restrict__ out) {
  __shared__ float Xs[9][LN];
  __shared__ float pool[9216];   // phase1/2: xe[9*720]; phase3: obuf[256*36]
  __shared__ int s_lid[8], s_shf[8];
  __shared__ float s_r[8];
  int b = blockIdx.x >> 7, c = blockIdx.x & 127;
  int t = threadIdx.x;
  if (t < 8) {
    int q = (((b << 7) + c) << 3) + t;
    s_lid[t] = lid[q]; s_shf[t] = shf[q]; s_r[t] = rv[q];
  }
  float* xe = pool;
  for (int l = t; l < LN; l += 256) xe[l] = x[(b * LN + l) * CCH + c];
  __syncthreads();
  for (int p = 1; p <= 8; p++) {
    float r = s_r[p - 1];
    if (fabsf(r) < 0.1f) {
      for (int l = t; l < LN; l += 256) xe[p * LN + l] = xe[l];
    } else {
      float sg = (r < 0.f) ? -1.f : 1.f;
      int ld = s_lid[p - 1], sh = s_shf[p - 1];
      for (int l = t; l < LN; l += 256) {
        int tt = l - sh; tt = tt < 0 ? 0 : (tt > 719 ? 719 : tt);
        xe[p * LN + l] = sg * x[(b * LN + tt) * CCH + ld];
      }
    }
  }
  __syncthreads();

  // Phase 2: X[p,k] = sum_l D[k,l]*xe[p,l]
  {
    int k0 = t, k1 = t + 256, k2 = t + 512;
    float a0[9], a1[9], a2[9];
#pragma unroll
    for (int p = 0; p < 9; p++) { a0[p] = 0.f; a1[p] = 0.f; a2[p] = 0.f; }
    const float* D0 = D + (size_t)k0 * LN;
    const float* D1 = D + (size_t)k1 * LN;
    const float* D2 = D + (size_t)(k2 < LN ? k2 : k0) * LN;
    for (int l = 0; l < LN; l++) {
      float xl[9];
#pragma unroll
      for (int p = 0; p < 9; p++) xl[p] = xe[p * LN + l];
      float d0 = D0[l], d1 = D1[l], d2 = D2[l];
#pragma unroll
      for (int p = 0; p < 9; p++) {
        a0[p] += d0 * xl[p];
        a1[p] += d1 * xl[p];
        a2[p] += d2 * xl[p];
      }
    }
#pragma unroll
    for (int p = 0; p < 9; p++) {
      Xs[p][k0] = a0[p];
      Xs[p][k1] = a1[p];
      if (k2 < LN) Xs[p][k2] = a2[p];
    }
  }
  __syncthreads();

  // Phase 3: bands, chunked over n for coalesced output
  float* obuf = pool;
  size_t outbase = (size_t)((b << 7) + c) * (LN * 36);
  for (int n0 = 0; n0 < LN; n0 += 256) {
    int nt = t & 63;
    int f = t >> 6;
    int nloc = nt * 4;
    int nchunk = (LN - n0 < 256) ? (LN - n0) : 256;
    bool act = (nloc < nchunk);
    float a[36];
#pragma unroll
    for (int q = 0; q < 36; q++) a[q] = 0.f;
    if (act) {
      const float* Dp = D + (size_t)(f * 180) * LN + (n0 + nloc);
      for (int k = 0; k < 180; k++) {
        float4 d = *(const float4*)Dp;
        Dp += LN;
        int kk = f * 180 + k;
#pragma unroll
        for (int p = 0; p < 9; p++) {
          float xv = Xs[p][kk];
          a[p * 4 + 0] += d.x * xv;
          a[p * 4 + 1] += d.y * xv;
          a[p * 4 + 2] += d.z * xv;
          a[p * 4 + 3] += d.w * xv;
        }
      }
#pragma unroll
      for (int p = 0; p < 9; p++)
#pragma unroll
        for (int nn = 0; nn < 4; nn++)
          obuf[(nloc + nn) * 36 + p * 4 + f] = a[p * 4 + nn];
    }
    __syncthreads();
    int tot = nchunk * 36;
    for (int idx = t; idx < tot; idx += 256)
      out[outbase + (size_t)n0 * 36 + idx] = obuf[idx];
    __syncthreads();
  }
}

// ---------------------------------------------------------------- launch
extern "C" void kernel_launch(void* const* d_in, const int* in_sizes, int n_in,
                              void* d_out, int out_size, void* d_ws, size_t ws_size,
                              hipStream_t stream) {
  const float* x = (const float*)d_in[0];
  float* out = (float*)d_out;

  char* ws = (char*)d_ws;
  double* ct  = (double*)ws;                      // 720
  double* st  = ct + 720;                         // 720
  double* Cm  = st + 720;                         // 361*720
  double* Sm  = Cm + NBIN * LN;                   // 361*720
  float*  nRr = (float*)(Sm + NBIN * LN);         // 1024*361
  float*  nIr = nRr + 1024 * NBIN;                // 1024*361
  float*  Mv  = nIr + 1024 * NBIN;                // 8*128*128
  float*  rv  = Mv + 8 * 128 * 128;               // 8*128*8
  float*  D   = rv + 8 * 128 * 8;                 // 720*720 (16B-aligned)
  int*    Mi  = (int*)(D + 720 * 720);            // 8*128*128
  int*    lid = Mi + 8 * 128 * 128;               // 8*128*8
  int*    shf = lid + 8 * 128 * 8;                // 8*128*8
  int2*   ptab = (int2*)(shf + 8 * 128 * 8);      // 8128

  k_twiddle<<<3, 256, 0, stream>>>(ct, st);
  k_wmat<<<(NBIN * LN + 255) / 256, 256, 0, stream>>>(ct, st, Cm, Sm);
  k_ptab<<<(NPAIRS + 255) / 256, 256, 0, stream>>>(ptab);
  k_dctmat<<<(720 * 720 + 255) / 256, 256, 0, stream>>>(D);
  k_rfft<<<8 * 128, 256, 0, stream>>>(x, ct, st, nRr, nIr);
  k_pc<<<8 * NPG, 192, 0, stream>>>(nRr, nIr, Cm, Sm, ptab, Mv, Mi);
  k_topk<<<8 * 128, 64, 0, stream>>>(Mv, Mi, lid, shf, rv);
  k_out<<<8 * 128, 256, 0, stream>>>(x, D, lid, shf, rv, out);
}

// Round 5
// 1922.236 us; speedup vs baseline: 1.9588x; 1.3278x over previous
//
#include <hip/hip_runtime.h>
#include <math.h>

#define LN   720
#define NBIN 361
#define CCH  128
#define NPAIRS 8128   // 128*127/2
#define NP     10     // pairs per k_pc block
#define NPG    813    // ceil(8128/10)
#define KCH    128    // k-chunk size for staged cross (3 chunks cover 361 bins)

// ---------------------------------------------------------------- tables
__global__ void k_twiddle(double* __restrict__ ct, double* __restrict__ st) {
  int m = blockIdx.x * 256 + threadIdx.x;
  if (m < LN) {
    double a = 6.2831853071795864769252867665590057684 * (double)m / 720.0;
    ct[m] = cos(a);
    st[m] = sin(a);
  }
}

// Cm[k*720+n] = ct[(k*n)%720], Sm likewise — bit-identical to the LDS gather values.
__global__ void k_wmat(const double* __restrict__ ct, const double* __restrict__ st,
                       double* __restrict__ Cm, double* __restrict__ Sm) {
  int idx = blockIdx.x * 256 + threadIdx.x;
  if (idx < NBIN * LN) {
    int k = idx / LN, n = idx - k * LN;
    int r = (int)(((long long)k * n) % LN);
    Cm[idx] = ct[r];
    Sm[idx] = st[r];
  }
}

__global__ void k_ptab(int2* __restrict__ ptab) {
  int p = blockIdx.x * 256 + threadIdx.x;
  if (p < NPAIRS) {
    int i = 0, rem = p;
    while (rem >= 127 - i) { rem -= 127 - i; i++; }
    ptab[p] = make_int2(i, i + 1 + rem);
  }
}

// D[k*720+l] and transposed Dt[l*720+k] (same values; Dt gives lane-coalesced
// phase-2 reads in k_out).
__global__ void k_dctmat(float* __restrict__ D, float* __restrict__ Dt) {
  int idx = blockIdx.x * 256 + threadIdx.x;
  if (idx < LN * LN) {
    int k = idx / LN, l = idx - k * LN;
    double ang = 3.1415926535897932384626433832795028842 * (double)((2 * l + 1) * k) / 1440.0;
    double v = cos(ang) * sqrt(2.0 / 720.0);
    if (k == 0) v *= 0.70710678118654752440084436210485;
    float f = (float)v;
    D[idx] = f;
    Dt[l * LN + k] = f;
  }
}

// ---------------------------------------------------------------- rfft (fp64 backbone) -> fp32-quantized nrf
__global__ __launch_bounds__(256) void k_rfft(const float* __restrict__ x,
                                              const double* __restrict__ ctg,
                                              const double* __restrict__ stg,
                                              float* __restrict__ nR,
                                              float* __restrict__ nI) {
  __shared__ double sd[LN];
  __shared__ double ctsP[768], stsP[768];
  int b = blockIdx.x >> 7, c = blockIdx.x & 127;
  int t = threadIdx.x;
  for (int m = t; m < LN; m += 256) {
    int a = m + (m >> 4);
    ctsP[a] = ctg[m]; stsP[a] = stg[m];
  }
  for (int l = t; l < LN; l += 256) sd[l] = (double)x[(b * LN + l) * CCH + c];
  __syncthreads();
  size_t gbase = (size_t)blockIdx.x * NBIN;
  for (int k = t; k < NBIN; k += 256) {
    double re = 0.0, im = 0.0;
    int idx = 0;
    for (int l = 0; l < LN; l++) {
      double s = sd[l];
      int a = idx + (idx >> 4);
      re += s * ctsP[a];
      im -= s * stsP[a];
      idx += k; if (idx >= LN) idx -= LN;
    }
    float reF = (float)re, imF = (float)im;        // complex64 quantization of rf
    float mag = hypotf(reF, imF);
    float d = fmaxf(mag, 1e-8f);
    nR[gbase + k] = __fdiv_rn(reF, d);
    nI[gbase + k] = __fdiv_rn(imF, d);
  }
}

// ---------------------------------------------------------------- phase correlation
// cross in strict fp32 (frozen invariant), irfft backbone fp64, k-ascending per
// accumulator. pc fp32-quantized before max/argmax; ties -> lowest index.
//
// Round 10: spill + latency fix on top of round 9.
//  - launch_bounds (192,2): round 9's (192,4) made the compiler allocate 64
//    VGPRs for ~110 of live state -> scratch spill (WRITE_SIZE 4->39MB) and
//    occupancy pinned at ~12 waves/CU. Let the allocator take what it needs.
//  - epilogue restructured p-outer so the per-p best arrays are scalars
//    (-40 VGPRs of peak pressure).
//  - 1-deep software prefetch of the next k's C/S table row overlaps the
//    L2 table-load latency with the 10-pair FMA burst.
// Math/order unchanged -> bit-identical.
__global__ __launch_bounds__(192, 2) void k_pc(const float* __restrict__ nR,
                                               const float* __restrict__ nI,
                                               const double* __restrict__ Cm,
                                               const double* __restrict__ Sm,
                                               const int2* __restrict__ ptab,
                                               float* __restrict__ Mv, int* __restrict__ Mi) {
  __shared__ float2 cC[NP][KCH];         // .x = Re, .y = Im (fp32 cross, one k-chunk)
  __shared__ int2 spair[NP];
  __shared__ float wv[3][NP][2];
  __shared__ int   wi[3][NP][2];
  __shared__ double sdc[NP], sny[NP];    // k=0 (dc) and k=360 (nyquist) Re terms
  int b = blockIdx.x / NPG;
  int pg = blockIdx.x - b * NPG;
  int pbase = pg * NP;
  int np = NPAIRS - pbase; if (np > NP) np = NP;
  int t = threadIdx.x;
  if (t < np) spair[t] = ptab[pbase + t];
  __syncthreads();

  // thread t owns bins n0 = t and n1 = t + 192 (n1 garbage when > 360; table
  // columns up to 719 exist so loads stay in-bounds, results discarded).
  int n0 = t, n1 = t + 192;
  double cosA[NP][2], sinA[NP][2];
#pragma unroll
  for (int p = 0; p < NP; p++) {
    cosA[p][0] = 0.0; cosA[p][1] = 0.0;
    sinA[p][0] = 0.0; sinA[p][1] = 0.0;
  }

  for (int ch = 0; ch < 3; ch++) {
    int klo = ch * KCH;
    // stage this k-chunk of cross (strict fp32)
    for (int v = t; v < np * KCH; v += 192) {
      int p = v >> 7, kk = v & (KCH - 1);
      int k = klo + kk;
      if (k < NBIN) {
        int i = spair[p].x, j = spair[p].y;
        size_t ib = ((size_t)(b << 7) + i) * NBIN + k;
        size_t jb = ((size_t)(b << 7) + j) * NBIN + k;
        float aR = nR[ib], aI = nI[ib];
        float bR = nR[jb], bI = nI[jb];
        float xr = __fadd_rn(__fmul_rn(aR, bR), __fmul_rn(aI, bI));
        float xi = __fsub_rn(__fmul_rn(aI, bR), __fmul_rn(aR, bI));
        cC[p][kk] = make_float2(xr, xi);
        if (k == 0)   sdc[p] = (double)xr;
        if (k == 360) sny[p] = (double)xr;
      }
    }
    __syncthreads();

    int kstart = (klo < 1) ? 1 : klo;
    int kend = klo + KCH; if (kend > 360) kend = 360;
    const double* Cr = Cm + (size_t)kstart * LN;
    const double* Sr = Sm + (size_t)kstart * LN;
    double C0 = Cr[n0], C1 = Cr[n1];
    double S0 = Sr[n0], S1 = Sr[n1];
    for (int k = kstart; k < kend; k++) {
      // prefetch next k's table row (k+1 <= 360 always; row exists)
      const double* Crn = Cm + (size_t)(k + 1) * LN;
      const double* Srn = Sm + (size_t)(k + 1) * LN;
      double nC0 = Crn[n0], nC1 = Crn[n1];
      double nS0 = Srn[n0], nS1 = Srn[n1];
      int kk = k - klo;
#pragma unroll
      for (int p = 0; p < NP; p++) {
        float2 cx = cC[p][kk];
        double cr = (double)cx.x, ci = (double)cx.y;
        cosA[p][0] = fma(cr, C0, cosA[p][0]);
        cosA[p][1] = fma(cr, C1, cosA[p][1]);
        sinA[p][0] = fma(ci, S0, sinA[p][0]);
        sinA[p][1] = fma(ci, S1, sinA[p][1]);
      }
      C0 = nC0; C1 = nC1; S0 = nS0; S1 = nS1;
    }
    __syncthreads();
  }

  // epilogue: fp32 quantize + argmax (both directions), p-outer so the
  // per-p bests are scalars (registers), not arrays.
  int lane = t & 63, w = t >> 6;
#pragma unroll
  for (int p = 0; p < NP; p++) {
    float bv1 = -3.0e38f, bv2 = -3.0e38f;
    int bi1 = 0x7fffffff, bi2 = 0x7fffffff;
    double dc = sdc[p], ny = sny[p];
#pragma unroll
    for (int q = 0; q < 2; q++) {
      int n = t + q * 192;
      if (n <= 360) {
        bool hasRev = (n >= 1) && (n <= 359);  // n=0 invalid; n=360 duplicate of fwd
        int idxF1 = n;                          // d0 index of pf_f
        int idxR1 = LN - n;                     // d0 index of pf_r
        int idxF2 = (n == 0) ? 0 : (LN - n);    // d1 index of pf_f
        int idxR2 = n;                          // d1 index of pf_r
        double sg = (n & 1) ? -ny : ny;
        double ca = cosA[p][q], sa = sinA[p][q];
        float pf_f = (float)((dc + sg + 2.0 * (ca - sa)) * (1.0 / 720.0));
        float pf_r = (float)((dc + sg + 2.0 * (ca + sa)) * (1.0 / 720.0));
        if (pf_f > bv1 || (pf_f == bv1 && idxF1 < bi1)) { bv1 = pf_f; bi1 = idxF1; }
        if (hasRev && (pf_r > bv1 || (pf_r == bv1 && idxR1 < bi1))) { bv1 = pf_r; bi1 = idxR1; }
        if (pf_f > bv2 || (pf_f == bv2 && idxF2 < bi2)) { bv2 = pf_f; bi2 = idxF2; }
        if (hasRev && (pf_r > bv2 || (pf_r == bv2 && idxR2 < bi2))) { bv2 = pf_r; bi2 = idxR2; }
      }
    }
    for (int off = 32; off >= 1; off >>= 1) {
      float ov = __shfl_down(bv1, off); int oi = __shfl_down(bi1, off);
      if (ov > bv1 || (ov == bv1 && oi < bi1)) { bv1 = ov; bi1 = oi; }
      float ov2 = __shfl_down(bv2, off); int oi2 = __shfl_down(bi2, off);
      if (ov2 > bv2 || (ov2 == bv2 && oi2 < bi2)) { bv2 = ov2; bi2 = oi2; }
    }
    if (lane == 0) {
      wv[w][p][0] = bv1; wi[w][p][0] = bi1;
      wv[w][p][1] = bv2; wi[w][p][1] = bi2;
    }
  }
  __syncthreads();
  if (t < NP * 2) {
    int p = t >> 1, d = t & 1;
    if (p < np) {
      float bv = wv[0][p][d]; int bi = wi[0][p][d];
      for (int ww = 1; ww < 3; ww++) {
        float ov = wv[ww][p][d]; int oi = wi[ww][p][d];
        if (ov > bv || (ov == bv && oi < bi)) { bv = ov; bi = oi; }
      }
      int i = spair[p].x, j = spair[p].y;
      int o = d ? ((((b << 7) + j) << 7) + i) : ((((b << 7) + i) << 7) + j);
      Mv[o] = bv; Mi[o] = bi;
    }
  }
}

// ---------------------------------------------------------------- top-8 (fp32, literal selection)
__global__ __launch_bounds__(64) void k_topk(const float* __restrict__ Mv, const int* __restrict__ Mi,
                                             int* __restrict__ lid, int* __restrict__ shf,
                                             float* __restrict__ rv) {
  int b = blockIdx.x >> 7, r = blockIdx.x & 127;
  if (threadIdx.x != 0) return;
  float sval[128]; int ssh[128];
  int base = (((b << 7) + r) << 7);
  for (int j = 0; j < 128; j++) {
    if (j == r) { sval[j] = -3.0e38f; ssh[j] = 0; continue; }
    float mvv = Mv[base + j]; int mii = Mi[base + j];
    sval[j] = mvv;
    ssh[j] = (mii > 360) ? (mii - 720) : mii;
  }
  for (int k = 0; k < 8; k++) {
    float best = -3.0e38f; int bj = 0;
    for (int j = 0; j < 128; j++)
      if (sval[j] > best) { best = sval[j]; bj = j; }
    int o = (((b << 7) + r) << 3) + k;
    lid[o] = bj; rv[o] = best; shf[o] = ssh[bj];
    sval[bj] = -3.0e38f;
  }
}

// ---------------------------------------------------------------- gather + DCT + bands (fp32, staged)
__global__ __launch_bounds__(256) void k_out(const float* __restrict__ x,
                                             const float* __restrict__ D,
                                             const float* __restrict__ Dt,
                                             const int* __restrict__ lid,
                                             const int* __restrict__ shf,
                                             const float* __restrict__ rv,
                                             float* __restrict__ out) {
  __shared__ float Xs[9][LN];
  __shared__ float pool[9216];   // phase1/2: xe[9*720]; phase3: obuf[256*36]
  __shared__ int s_lid[8], s_shf[8];
  __shared__ float s_r[8];
  int b = blockIdx.x >> 7, c = blockIdx.x & 127;
  int t = threadIdx.x;
  if (t < 8) {
    int q = (((b << 7) + c) << 3) + t;
    s_lid[t] = lid[q]; s_shf[t] = shf[q]; s_r[t] = rv[q];
  }
  float* xe = pool;
  for (int l = t; l < LN; l += 256) xe[l] = x[(b * LN + l) * CCH + c];
  __syncthreads();
  for (int p = 1; p <= 8; p++) {
    float r = s_r[p - 1];
    if (fabsf(r) < 0.1f) {
      for (int l = t; l < LN; l += 256) xe[p * LN + l] = xe[l];
    } else {
      float sg = (r < 0.f) ? -1.f : 1.f;
      int ld = s_lid[p - 1], sh = s_shf[p - 1];
      for (int l = t; l < LN; l += 256) {
        int tt = l - sh; tt = tt < 0 ? 0 : (tt > 719 ? 719 : tt);
        xe[p * LN + l] = sg * x[(b * LN + tt) * CCH + ld];
      }
    }
  }
  __syncthreads();

  // Phase 2: X[p,k] = sum_l D[k,l]*xe[p,l]. Reads via Dt[l*720+k] so lane k
  // is consecutive -> coalesced (D[k*720+l] had 2880B lane stride).
  {
    int k0 = t, k1 = t + 256, k2 = t + 512;
    int k2c = (k2 < LN) ? k2 : k0;
    float a0[9], a1[9], a2[9];
#pragma unroll
    for (int p = 0; p < 9; p++) { a0[p] = 0.f; a1[p] = 0.f; a2[p] = 0.f; }
    const float* DtRow = Dt;
    for (int l = 0; l < LN; l++) {
      float xl[9];
#pragma unroll
      for (int p = 0; p < 9; p++) xl[p] = xe[p * LN + l];
      float d0 = DtRow[k0], d1 = DtRow[k1], d2 = DtRow[k2c];
      DtRow += LN;
#pragma unroll
      for (int p = 0; p < 9; p++) {
        a0[p] += d0 * xl[p];
        a1[p] += d1 * xl[p];
        a2[p] += d2 * xl[p];
      }
    }
#pragma unroll
    for (int p = 0; p < 9; p++) {
      Xs[p][k0] = a0[p];
      Xs[p][k1] = a1[p];
      if (k2 < LN) Xs[p][k2] = a2[p];
    }
  }
  __syncthreads();

  // Phase 3: bands, chunked over n for coalesced output
  float* obuf = pool;
  size_t outbase = (size_t)((b << 7) + c) * (LN * 36);
  for (int n0 = 0; n0 < LN; n0 += 256) {
    int nt = t & 63;
    int f = t >> 6;
    int nloc = nt * 4;
    int nchunk = (LN - n0 < 256) ? (LN - n0) : 256;
    bool act = (nloc < nchunk);
    float a[36];
#pragma unroll
    for (int q = 0; q < 36; q++) a[q] = 0.f;
    if (act) {
      const float* Dp = D + (size_t)(f * 180) * LN + (n0 + nloc);
      for (int k = 0; k < 180; k++) {
        float4 d = *(const float4*)Dp;
        Dp += LN;
        int kk = f * 180 + k;
#pragma unroll
        for (int p = 0; p < 9; p++) {
          float xv = Xs[p][kk];
          a[p * 4 + 0] += d.x * xv;
          a[p * 4 + 1] += d.y * xv;
          a[p * 4 + 2] += d.z * xv;
          a[p * 4 + 3] += d.w * xv;
        }
      }
#pragma unroll
      for (int p = 0; p < 9; p++)
#pragma unroll
        for (int nn = 0; nn < 4; nn++)
          obuf[(nloc + nn) * 36 + p * 4 + f] = a[p * 4 + nn];
    }
    __syncthreads();
    int tot = nchunk * 36;
    for (int idx = t; idx < tot; idx += 256)
      out[outbase + (size_t)n0 * 36 + idx] = obuf[idx];
    __syncthreads();
  }
}

// ---------------------------------------------------------------- launch
extern "C" void kernel_launch(void* const* d_in, const int* in_sizes, int n_in,
                              void* d_out, int out_size, void* d_ws, size_t ws_size,
                              hipStream_t stream) {
  const float* x = (const float*)d_in[0];
  float* out = (float*)d_out;

  char* ws = (char*)d_ws;
  double* ct  = (double*)ws;                      // 720
  double* st  = ct + 720;                         // 720
  double* Cm  = st + 720;                         // 361*720
  double* Sm  = Cm + NBIN * LN;                   // 361*720
  float*  nRr = (float*)(Sm + NBIN * LN);         // 1024*361
  float*  nIr = nRr + 1024 * NBIN;                // 1024*361
  float*  Mv  = nIr + 1024 * NBIN;                // 8*128*128
  float*  rv  = Mv + 8 * 128 * 128;               // 8*128*8
  float*  D   = rv + 8 * 128 * 8;                 // 720*720 (16B-aligned)
  float*  Dt  = D + 720 * 720;                    // 720*720 transposed copy
  int*    Mi  = (int*)(Dt + 720 * 720);           // 8*128*128
  int*    lid = Mi + 8 * 128 * 128;               // 8*128*8
  int*    shf = lid + 8 * 128 * 8;                // 8*128*8
  int2*   ptab = (int2*)(shf + 8 * 128 * 8);      // 8128

  k_twiddle<<<3, 256, 0, stream>>>(ct, st);
  k_wmat<<<(NBIN * LN + 255) / 256, 256, 0, stream>>>(ct, st, Cm, Sm);
  k_ptab<<<(NPAIRS + 255) / 256, 256, 0, stream>>>(ptab);
  k_dctmat<<<(720 * 720 + 255) / 256, 256, 0, stream>>>(D, Dt);
  k_rfft<<<8 * 128, 256, 0, stream>>>(x, ct, st, nRr, nIr);
  k_pc<<<8 * NPG, 192, 0, stream>>>(nRr, nIr, Cm, Sm, ptab, Mv, Mi);
  k_topk<<<8 * 128, 64, 0, stream>>>(Mv, Mi, lid, shf, rv);
  k_out<<<8 * 128, 256, 0, stream>>>(x, D, Dt, lid, shf, rv, out);
}